// Round 1
// baseline (232.857 us; speedup 1.0000x reference)
//
#include <hip/hip_runtime.h>

#define DD 128
#define NP 8
#define NK 4
#define NB 65536

// ---------------------------------------------------------------------------
// K1: per-column attention weights + weighted combine + relu + +q + LN stats.
// Thread per batch column. Two streaming passes over q/keys (coalesced).
// Writes y = relu(sum_n w_n key_n) + q  to d_out, and (mu, rstd) to ws.
// ---------------------------------------------------------------------------
__global__ __launch_bounds__(256) void k1_attn_combine(
    const float* __restrict__ q, const float* __restrict__ keys,
    const float* __restrict__ A, float* __restrict__ y,
    float* __restrict__ mu_o, float* __restrict__ rs_o)
{
    const int b = blockIdx.x * 256 + threadIdx.x;

    // ---- pass 1: dot products against atten_vecs -------------------------
    float qd[NK] = {0.f, 0.f, 0.f, 0.f};
    float kd[NP][NK];
    #pragma unroll
    for (int n = 0; n < NP; ++n)
        #pragma unroll
        for (int k = 0; k < NK; ++k) kd[n][k] = 0.f;

    #pragma unroll 4
    for (int d = 0; d < DD; ++d) {
        float at[NK], ab[NK];
        #pragma unroll
        for (int k = 0; k < NK; ++k) {          // uniform -> s_load
            at[k] = A[d * NK + k];
            ab[k] = A[(DD + d) * NK + k];
        }
        const float qv = q[d * NB + b];
        #pragma unroll
        for (int k = 0; k < NK; ++k) qd[k] += qv * at[k];
        #pragma unroll
        for (int n = 0; n < NP; ++n) {
            const float kv = keys[(n * DD + d) * NB + b];
            #pragma unroll
            for (int k = 0; k < NK; ++k) kd[n][k] += kv * ab[k];
        }
    }

    // ---- leaky_relu + softmax over n (per k); w_n = 0.25 * sum_k s[n][k] --
    float z[NP][NK];
    float mx[NK] = {-3.4e38f, -3.4e38f, -3.4e38f, -3.4e38f};
    #pragma unroll
    for (int n = 0; n < NP; ++n)
        #pragma unroll
        for (int k = 0; k < NK; ++k) {
            float v = qd[k] + kd[n][k];
            v = (v >= 0.f) ? v : 0.01f * v;     // leaky_relu(0.01)
            z[n][k] = v;
            mx[k] = fmaxf(mx[k], v);
        }
    float S[NK] = {0.f, 0.f, 0.f, 0.f};
    #pragma unroll
    for (int n = 0; n < NP; ++n)
        #pragma unroll
        for (int k = 0; k < NK; ++k) {
            const float e = __expf(z[n][k] - mx[k]);
            z[n][k] = e;
            S[k] += e;
        }
    float r[NK];
    #pragma unroll
    for (int k = 0; k < NK; ++k) r[k] = 1.f / S[k];
    float w[NP];
    #pragma unroll
    for (int n = 0; n < NP; ++n)
        w[n] = 0.25f * (z[n][0] * r[0] + z[n][1] * r[1] +
                        z[n][2] * r[2] + z[n][3] * r[3]);

    // ---- pass 2: weighted combine + relu + residual q + LN stats ---------
    float sum = 0.f, ssq = 0.f;
    #pragma unroll 4
    for (int d = 0; d < DD; ++d) {
        float acc = 0.f;
        #pragma unroll
        for (int n = 0; n < NP; ++n) acc += w[n] * keys[(n * DD + d) * NB + b];
        const float yv = fmaxf(acc, 0.f) + q[d * NB + b];
        y[d * NB + b] = yv;
        sum += yv;
        ssq += yv * yv;
    }
    const float mu  = sum * (1.f / DD);
    const float var = ssq * (1.f / DD) - mu * mu;
    mu_o[b] = mu;
    rs_o[b] = rsqrtf(var + 1e-6f);
}

// ---------------------------------------------------------------------------
// K2: c = LN1(y); linear = W@c + B + c; out = LN2(linear).
// 256 threads = 64 columns x 4 d-quarters (quarter == wave -> W rows are
// wave-uniform; readfirstlane forces scalar loads for W/bias/gamma rows).
// c[128] lives in registers (static indices only). y2 tile staged in LDS
// for the post-stats re-read. In-place over d_out is safe: all y reads
// happen before the block barrier, all out writes after it.
// ---------------------------------------------------------------------------
__global__ __launch_bounds__(256) void k2_post(
    const float* y, const float* __restrict__ mu_a, const float* __restrict__ rs_a,
    const float* __restrict__ g1, const float* __restrict__ b1,
    const float* __restrict__ W,  const float* __restrict__ Bv,
    const float* __restrict__ g2, const float* __restrict__ b2,
    float* out)
{
    __shared__ float y2s[DD][64];
    __shared__ float red[4][64][2];
    const int col = threadIdx.x & 63;
    const int qtr = threadIdx.x >> 6;          // == wave id
    const int b   = blockIdx.x * 64 + col;
    const float mu = mu_a[b], rs = rs_a[b];

    // c = LN1(y) for this column, registers, static indices
    float c[DD];
    #pragma unroll
    for (int j = 0; j < DD; ++j)
        c[j] = g1[j] * ((y[j * NB + b] - mu) * rs) + b1[j];

    float psum = 0.f, pssq = 0.f;
    const int dbase = qtr * 32;
    for (int i = 0; i < 32; ++i) {
        // force wave-uniformity so W/g/b rows become s_loads
        const int d = __builtin_amdgcn_readfirstlane(dbase + i);
        float a0 = 0.f, a1 = 0.f, a2 = 0.f, a3 = 0.f;
        #pragma unroll
        for (int j = 0; j < DD; j += 4) {
            a0 += W[d * DD + j + 0] * c[j + 0];
            a1 += W[d * DD + j + 1] * c[j + 1];
            a2 += W[d * DD + j + 2] * c[j + 2];
            a3 += W[d * DD + j + 3] * c[j + 3];
        }
        // recompute c[d] from y (avoids runtime-indexing the c[] array)
        const float cd = g1[d] * ((y[d * NB + b] - mu) * rs) + b1[d];
        const float v  = Bv[d] + ((a0 + a1) + (a2 + a3)) + cd;
        y2s[d][col] = v;
        psum += v;
        pssq += v * v;
    }
    red[qtr][col][0] = psum;
    red[qtr][col][1] = pssq;
    __syncthreads();
    const float ts = red[0][col][0] + red[1][col][0] + red[2][col][0] + red[3][col][0];
    const float tq = red[0][col][1] + red[1][col][1] + red[2][col][1] + red[3][col][1];
    const float mu2 = ts * (1.f / DD);
    const float rs2 = rsqrtf(tq * (1.f / DD) - mu2 * mu2 + 1e-6f);
    for (int i = 0; i < 32; ++i) {
        const int d = __builtin_amdgcn_readfirstlane(dbase + i);
        const float v = y2s[d][col];
        out[d * NB + b] = g2[d] * ((v - mu2) * rs2) + b2[d];
    }
}

extern "C" void kernel_launch(void* const* d_in, const int* in_sizes, int n_in,
                              void* d_out, int out_size, void* d_ws, size_t ws_size,
                              hipStream_t stream)
{
    const float* q    = (const float*)d_in[0];  // [1,128,65536]
    const float* keys = (const float*)d_in[1];  // [8,128,65536]
    const float* A    = (const float*)d_in[2];  // [256,4]
    const float* g1   = (const float*)d_in[3];  // [128]
    const float* b1   = (const float*)d_in[4];  // [128]
    const float* W    = (const float*)d_in[5];  // [128,128]
    const float* Bv   = (const float*)d_in[6];  // [128,1]
    const float* g2   = (const float*)d_in[7];  // [128]
    const float* b2   = (const float*)d_in[8];  // [128]
    float* out = (float*)d_out;                 // [128,65536]

    float* mu = (float*)d_ws;                   // [65536]
    float* rs = mu + NB;                        // [65536]

    k1_attn_combine<<<NB / 256, 256, 0, stream>>>(q, keys, A, out, mu, rs);
    k2_post<<<NB / 64, 256, 0, stream>>>(out, mu, rs, g1, b1, W, Bv, g2, b2, out);
}